// Round 2
// baseline (1108.785 us; speedup 1.0000x reference)
//
#include <hip/hip_runtime.h>
#include <hip/hip_bf16.h>
#include <stdint.h>

typedef float f32x4 __attribute__((ext_vector_type(4)));
typedef short short8 __attribute__((ext_vector_type(8)));

#define NSP 128
#define LDSPAD 136   // row stride (bf16 elems): 272B = 68 dwords -> conflict-free b128 phases

__device__ __forceinline__ unsigned short f2bf(float f) {
    union { float f; uint32_t u; } x; x.f = f;
    uint32_t r = (x.u + 0x7FFFu + ((x.u >> 16) & 1u)) >> 16;  // RNE
    return (unsigned short)r;
}
__device__ __forceinline__ uint32_t pack2(float a, float b) {
    return (uint32_t)f2bf(a) | ((uint32_t)f2bf(b) << 16);
}
// tanh(z) given z2 = 2z :  1 - 2/(1+e^{2z})
__device__ __forceinline__ float fast_tanh2(float z2) {
    float e = __expf(z2);
    return 1.0f - 2.0f * __builtin_amdgcn_rcpf(e + 1.0f);
}
// log(2*cosh(y)) = |y| + log(1 + e^{-2|y|})
__device__ __forceinline__ float log2cosh(float y) {
    float a = fabsf(y);
    return a + __logf(1.0f + __expf(-2.0f * a));
}

__global__ __launch_bounds__(128, 2)
void mf_ising(const float* __restrict__ feat, const float* __restrict__ lf,
              const float* __restrict__ Jg, float* __restrict__ out) {
    __shared__ __align__(16) unsigned short JT[NSP * LDSPAD];  // J^T, diag zeroed, bf16
    __shared__ __align__(16) unsigned short SL[64 * LDSPAD];   // spins, 32 rows per wave (private)

    const int tid  = threadIdx.x;
    const int wave = tid >> 6;
    const int lane = tid & 63;
    const int j    = lane & 15;   // batch row within 16-tile (MFMA col / A row)
    const int g    = lane >> 4;   // k-group

    // ---- stage J^T into LDS (bf16, zero diagonal). Coalesced global reads.
    #pragma unroll 4
    for (int c = 0; c < 128; ++c) {
        int flat = c * 128 + tid;          // flat = k*128 + i  (J is [k][i] row-major)
        int k = flat >> 7, i = flat & 127;
        float v = (i == k) ? 0.0f : Jg[flat];
        JT[i * LDSPAD + k] = f2bf(v);
    }

    const int rowBase = blockIdx.x * 64 + wave * 32;

    // local field per lane: lf[16*it + 4*g + r]
    f32x4 lfv[8];
    #pragma unroll
    for (int it = 0; it < 8; ++it)
        lfv[it] = *(const f32x4*)(lf + it * 16 + g * 4);

    // spins in C'-layout registers: sreg[jt][it][r] = s[row = rowBase+jt*16+j][spin = 16*it+4*g+r]
    f32x4 sreg[2][8];
    #pragma unroll
    for (int jt = 0; jt < 2; ++jt) {
        const size_t row = (size_t)(rowBase + jt * 16 + j);
        #pragma unroll
        for (int it = 0; it < 8; ++it) {
            f32x4 fv = *(const f32x4*)(feat + row * NSP + it * 16 + g * 4);
            f32x4 s;
            #pragma unroll
            for (int r = 0; r < 4; ++r) s[r] = fast_tanh2(0.2f * fv[r]);  // tanh(0.1*f)
            sreg[jt][it] = s;
        }
    }
    __syncthreads();   // JT ready; SL is wave-private so no barriers in the loop

    f32x4 acc[8][2];   // h in C'-layout: acc[it][jt][r] = h[row jt..][spin 16*it+4*g+r]

    auto matvec = [&]() {
        // stage spins -> LDS bf16 (4 contiguous spins per lane -> ds_write_b64)
        #pragma unroll
        for (int jt = 0; jt < 2; ++jt) {
            unsigned short* srow = &SL[(wave * 32 + jt * 16 + j) * LDSPAD];
            #pragma unroll
            for (int it = 0; it < 8; ++it) {
                uint2 v;
                v.x = pack2(sreg[jt][it][0], sreg[jt][it][1]);
                v.y = pack2(sreg[jt][it][2], sreg[jt][it][3]);
                *(uint2*)(srow + it * 16 + g * 4) = v;
            }
        }
        #pragma unroll
        for (int it = 0; it < 8; ++it) { acc[it][0] = lfv[it]; acc[it][1] = lfv[it]; }
        // C'[i][j] = sum_k J^T[i][k] * s^T[k][j]   (A = J^T frags, B = s frags)
        #pragma unroll
        for (int kt = 0; kt < 4; ++kt) {
            short8 b0 = *(const short8*)(&SL[(wave * 32 +      j) * LDSPAD + kt * 32 + g * 8]);
            short8 b1 = *(const short8*)(&SL[(wave * 32 + 16 + j) * LDSPAD + kt * 32 + g * 8]);
            #pragma unroll
            for (int it = 0; it < 8; ++it) {
                short8 a = *(const short8*)(&JT[(it * 16 + j) * LDSPAD + kt * 32 + g * 8]);
                acc[it][0] = __builtin_amdgcn_mfma_f32_16x16x32_bf16(a, b0, acc[it][0], 0, 0, 0);
                acc[it][1] = __builtin_amdgcn_mfma_f32_16x16x32_bf16(a, b1, acc[it][1], 0, 0, 0);
            }
        }
    };

    #pragma unroll 1
    for (int t = 0; t < 25; ++t) {
        matvec();                               // acc = lf + s @ Jm
        #pragma unroll
        for (int jt = 0; jt < 2; ++jt) {
            #pragma unroll
            for (int it = 0; it < 8; ++it) {
                f32x4 s = sreg[jt][it], h = acc[it][jt];
                #pragma unroll
                for (int r = 0; r < 4; ++r) {
                    float nw = fast_tanh2(8.0f * h[r]);     // tanh(h/GAMMA), 2*(4h)=8h
                    s[r] = 0.7f * nw + 0.3f * s[r];         // damped update
                }
                sreg[jt][it] = s;
            }
        }
    }
    matvec();   // h_final in acc, final spins in sreg

    // ---- outputs (FLOAT32): spins [B,S] then free_energy [B,1], concatenated
    #pragma unroll
    for (int jt = 0; jt < 2; ++jt) {
        const size_t row = (size_t)(rowBase + jt * 16 + j);
        #pragma unroll
        for (int it = 0; it < 8; ++it) {
            *(f32x4*)(out + row * NSP + it * 16 + g * 4) = sreg[jt][it];
        }
    }
    #pragma unroll
    for (int jt = 0; jt < 2; ++jt) {
        float p = 0.0f;
        #pragma unroll
        for (int it = 0; it < 8; ++it) {
            f32x4 h = acc[it][jt];
            #pragma unroll
            for (int r = 0; r < 4; ++r) p += log2cosh(4.0f * h[r]);
        }
        p += __shfl_xor(p, 16, 64);
        p += __shfl_xor(p, 32, 64);   // reduce across the 4 g-groups holding this row
        if (lane < 16) {
            size_t row = (size_t)(rowBase + jt * 16 + j);
            out[(size_t)262144 * NSP + row] = -0.25f * p;
        }
    }
}

extern "C" void kernel_launch(void* const* d_in, const int* in_sizes, int n_in,
                              void* d_out, int out_size, void* d_ws, size_t ws_size,
                              hipStream_t stream) {
    const float* feat = (const float*)d_in[0];
    const float* lfld = (const float*)d_in[1];
    const float* Jg   = (const float*)d_in[2];
    float* out = (float*)d_out;
    (void)in_sizes; (void)n_in; (void)out_size; (void)d_ws; (void)ws_size;

    dim3 grid(262144 / 64), block(128);
    hipLaunchKernelGGL(mf_ising, grid, block, 0, stream, feat, lfld, Jg, out);
}

// Round 3
// 509.621 us; speedup vs baseline: 2.1757x; 2.1757x over previous
//
#include <hip/hip_runtime.h>
#include <hip/hip_bf16.h>
#include <stdint.h>

typedef float f32x4 __attribute__((ext_vector_type(4)));
typedef short short8 __attribute__((ext_vector_type(8)));

#define LDSPAD 136            // bf16 elems per row: 272B rows, 16B-aligned (272=17*16)
#define C8 11.54156509f       // 8*log2(e): exp(8h) = exp2(C8*h)

static __device__ __forceinline__ unsigned short f2bf(float f) {
    union { float f; uint32_t u; } x; x.f = f;
    return (unsigned short)((x.u + 0x7FFFu + ((x.u >> 16) & 1u)) >> 16);  // RNE
}
static __device__ __forceinline__ uint32_t pk2(float a, float b) {
    float2 t; t.x = a; t.y = b;
    union { __hip_bfloat162 h; uint32_t u; } c;
    c.h = __float22bfloat162_rn(t);           // should fuse to v_cvt_pk_bf16_f32
    return c.u;
}
// tanh(z) with arg = 2z*log2(e):  1 - 2/(1+exp2(arg))
static __device__ __forceinline__ float tanh_e2(float arg) {
    float E = __builtin_amdgcn_exp2f(arg);
    return __builtin_fmaf(-2.0f, __builtin_amdgcn_rcpf(E + 1.0f), 1.0f);
}

__global__ __launch_bounds__(256, 2)
void mf_ising(const float* __restrict__ feat, const float* __restrict__ lf,
              const float* __restrict__ Jg, float* __restrict__ out) {
    // One buffer, two lives: [0] J^T staging (128 rows), then spin rows (64 rows).
    __shared__ __align__(16) unsigned short LB[128 * LDSPAD];   // 34.8 KB

    const int tid  = threadIdx.x;
    const int wave = tid >> 6;
    const int lane = tid & 63;
    const int j    = lane & 15;   // batch row within the wave's 16-row tile
    const int g    = lane >> 4;   // k-group

    // ---- stage J^T (bf16, diag zeroed) into LDS; coalesced f32 reads
    #pragma unroll 4
    for (int c = 0; c < 64; ++c) {
        int flat = c * 256 + tid;            // flat = k*128 + i
        int k = flat >> 7, i = flat & 127;
        float v = (i == k) ? 0.0f : Jg[flat];
        LB[i * LDSPAD + k] = f2bf(v);
    }
    __syncthreads();

    // ---- hoist ALL of J^T into registers: aFr[it][kt] = A-frag rows 16it+j, k=32kt+8g..+7
    short8 aFr[8][4];
    #pragma unroll
    for (int it = 0; it < 8; ++it)
        #pragma unroll
        for (int kt = 0; kt < 4; ++kt)
            aFr[it][kt] = *(const short8*)&LB[(16 * it + j) * LDSPAD + 32 * kt + 8 * g];
    __syncthreads();   // everyone done reading JT; LB now becomes the spin buffer

    const int rowBase = blockIdx.x * 64 + wave * 16;
    unsigned short* SL = &LB[(wave * 16) * LDSPAD];   // this wave's 16 spin rows (private)

    // local field (f32): lfv[it][r] = lf[16it+4g+r]; rides MFMA C-operand at kt=0
    f32x4 lfv[8];
    #pragma unroll
    for (int it = 0; it < 8; ++it)
        lfv[it] = *(const f32x4*)(lf + it * 16 + g * 4);

    // spins in C'-layout regs: sreg[it][r] = s[row=rowBase+j][spin=16it+4g+r]
    f32x4 sreg[8];
    {
        const size_t row = (size_t)(rowBase + j);
        #pragma unroll
        for (int it = 0; it < 8; ++it) {
            f32x4 fv = *(const f32x4*)(feat + row * 128 + it * 16 + g * 4);
            f32x4 s;
            #pragma unroll
            for (int r = 0; r < 4; ++r) s[r] = tanh_e2(0.28853901f * fv[r]); // tanh(0.1f)
            sreg[it] = s;
        }
    }

    f32x4 acc[8];   // h_eff in C'-layout (includes lf via C-init)

    auto matvec = [&]() {
        // spins -> LDS bf16 (wave-private rows; no barrier needed)
        unsigned short* srow = &SL[j * LDSPAD];
        #pragma unroll
        for (int it = 0; it < 8; ++it) {
            uint2 v;
            v.x = pk2(sreg[it][0], sreg[it][1]);
            v.y = pk2(sreg[it][2], sreg[it][3]);
            *(uint2*)(srow + it * 16 + g * 4) = v;
        }
        // C'[i][j] = lf[i] + sum_k J^T[i][k] s^T[k][j]
        #pragma unroll
        for (int kt = 0; kt < 4; ++kt) {
            short8 b = *(const short8*)&SL[j * LDSPAD + kt * 32 + g * 8];
            if (kt == 0) {
                #pragma unroll
                for (int it = 0; it < 8; ++it)
                    acc[it] = __builtin_amdgcn_mfma_f32_16x16x32_bf16(aFr[it][0], b, lfv[it], 0, 0, 0);
            } else {
                #pragma unroll
                for (int it = 0; it < 8; ++it)
                    acc[it] = __builtin_amdgcn_mfma_f32_16x16x32_bf16(aFr[it][kt], b, acc[it], 0, 0, 0);
            }
        }
    };

    #pragma unroll 1
    for (int t = 0; t < 25; ++t) {
        matvec();                                  // acc = lf + s@Jm
        #pragma unroll
        for (int it = 0; it < 8; ++it) {
            f32x4 s = sreg[it], h = acc[it];
            #pragma unroll
            for (int r = 0; r < 4; ++r) {
                float E = __builtin_amdgcn_exp2f(h[r] * C8);               // e^{8h}
                float rc = __builtin_amdgcn_rcpf(E + 1.0f);
                // s' = 0.7*tanh(4h) + 0.3*s = (0.3s + 0.7) - 1.4/(1+E)
                s[r] = __builtin_fmaf(-1.4f, rc, __builtin_fmaf(0.3f, s[r], 0.7f));
            }
            sreg[it] = s;
        }
    }
    matvec();   // final h_eff in acc, final spins in sreg

    // ---- outputs (f32): spins [B,128] then free_energy [B,1]
    {
        const size_t row = (size_t)(rowBase + j);
        #pragma unroll
        for (int it = 0; it < 8; ++it)
            *(f32x4*)(out + row * 128 + it * 16 + g * 4) = sreg[it];
    }
    float p = 0.0f;
    #pragma unroll
    for (int it = 0; it < 8; ++it) {
        #pragma unroll
        for (int r = 0; r < 4; ++r) {
            float y = 4.0f * acc[it][r];
            float a = fabsf(y);
            float q = __builtin_amdgcn_exp2f(-2.88539008f * a);            // e^{-2|y|}
            p += a + 0.69314718f * __builtin_amdgcn_logf(1.0f + q);        // |y|+log1p(..)
        }
    }
    p += __shfl_xor(p, 16, 64);
    p += __shfl_xor(p, 32, 64);
    if (lane < 16) {
        size_t row = (size_t)(rowBase + j);
        out[(size_t)262144 * 128 + row] = -0.25f * p;
    }
}

extern "C" void kernel_launch(void* const* d_in, const int* in_sizes, int n_in,
                              void* d_out, int out_size, void* d_ws, size_t ws_size,
                              hipStream_t stream) {
    const float* feat = (const float*)d_in[0];
    const float* lfld = (const float*)d_in[1];
    const float* Jg   = (const float*)d_in[2];
    float* out = (float*)d_out;
    (void)in_sizes; (void)n_in; (void)out_size; (void)d_ws; (void)ws_size;

    dim3 grid(262144 / 64), block(256);
    hipLaunchKernelGGL(mf_ising, grid, block, 0, stream, feat, lfld, Jg, out);
}